// Round 17
// baseline (49.234 us; speedup 1.0000x reference)
//
#include <hip/hip_runtime.h>

#define N_    32
#define CIN   128
#define H_    56
#define W_    56
#define HW_   (H_ * W_)
#define COUT  256
#define GROUPS 4
#define CPG   32      // in-channels per group
#define OPG   64      // out-channels per group
#define CDIM  64
#define HP    58      // padded spatial dim (1-px zero halo each side)

#define TH    4               // output rows per block (zero-tail geometry)
#define NPIX  (TH * W_)       // 224
#define NT    (NPIX / 16)     // 14 pixel tiles per wave
#define ROWB  (HP * CPG)      // bf16 per padded row = 1856 (3712 B)
#define ROW4  232             // dwordx4 per row
#define SCHUNKS 22            // ceil(6*3712/1024) staging chunks
#define LDS_B (SCHUNKS * 1024)

// fallback-path tile geometry (R2 kernel)
#define FB_TH   8
#define HALO_R (FB_TH + 2)
#define HALO_C (W_ + 2)
#define XPLANE (HALO_R * HALO_C)

typedef __bf16 bf16x8 __attribute__((ext_vector_type(8)));
typedef __bf16 bf16x2 __attribute__((ext_vector_type(2)));
typedef float  f32x4  __attribute__((ext_vector_type(4)));
typedef unsigned int u32x4 __attribute__((ext_vector_type(4)));

__device__ __forceinline__ void gload16(const void* g, void* l) {
    __builtin_amdgcn_global_load_lds((const __attribute__((address_space(1))) void*)g,
                                     (__attribute__((address_space(3))) void*)l, 16, 0, 0);
}

__device__ __forceinline__ uint packbf2(float a, float b) {
    bf16x2 v; v[0] = (__bf16)a; v[1] = (__bf16)b;
    return __builtin_bit_cast(unsigned int, v);
}

// ---------- merged pre-kernel (R13, vectorized): xpose (7424) + ctx (32) + wconv (36) ----------
// xt layout: [n][g][58 rows][58 pixels][4 slots][8 ic] bf16; octet o of pixel pix
// stored at slot o ^ ((pix>>1)&3). float4 reads, dwordx4 writes.
__global__ __launch_bounds__(256) void pre_kernel(
    const float* __restrict__ x, const float* __restrict__ c,
    const float* __restrict__ wgt, const float* __restrict__ bias,
    const float* __restrict__ cw,
    __bf16* __restrict__ xt, float* __restrict__ gctx, __bf16* __restrict__ wbf)
{
    const int bid = blockIdx.x;
    const int tid = threadIdx.x;

    if (bid < HP * GROUPS * N_) {                 // ---- xpose (one padded row) ----
        const int hh = bid % HP;
        const int g  = (bid / HP) & (GROUPS - 1);
        const int n  = bid / (HP * GROUPS);
        u32x4* drow4 = (u32x4*)(xt + ((size_t)(n * GROUPS + g) * HP + hh) * ROWB);
        const int h = hh - 1;
        if ((unsigned)h >= (unsigned)H_) {        // top/bottom halo row: zeros
            if (tid < ROW4) drow4[tid] = (u32x4){0u, 0u, 0u, 0u};
            return;
        }
        __shared__ float t[CPG][57];              // [ic][w]; pad 57
        const float* src = x + ((size_t)(n * CIN + g * CPG) * H_ + h) * W_;
        for (int j = tid; j < CPG * (W_ / 4); j += 256) {
            int ic = j / 14, q = j - ic * 14;
            f32x4 v = *(const f32x4*)&src[(size_t)ic * HW_ + q * 4];
            #pragma unroll
            for (int k = 0; k < 4; ++k) t[ic][q * 4 + k] = v[k];
        }
        __syncthreads();
        if (tid < ROW4) {
            int pix = tid >> 2;
            int oct = (tid & 3) ^ ((pix >> 1) & 3);
            int w = pix - 1;
            u32x4 o4 = {0u, 0u, 0u, 0u};
            if ((unsigned)w < (unsigned)W_) {
                #pragma unroll
                for (int dd = 0; dd < 4; ++dd)
                    o4[dd] = packbf2(t[oct * 8 + dd * 2][w], t[oct * 8 + dd * 2 + 1][w]);
            }
            drow4[tid] = o4;
        }
    } else if (bid < HP * GROUPS * N_ + N_) {     // ---- ctx ----
        const int n  = bid - HP * GROUPS * N_;
        const int oc = tid;
        const float* cn  = c  + n * CDIM;
        const float* cwo = cw + oc * CDIM;
        float s = bias[oc];
        #pragma unroll
        for (int d = 0; d < CDIM; ++d) s += cn[d] * cwo[d];
        gctx[n * COUT + oc] = s;
    } else {                                      // ---- wconv: bf16 [g][tap][oct][ocL][8] ----
        int j = (bid - (HP * GROUPS * N_ + N_)) * 256 + tid;
        int e   = j & 7;
        int r   = j >> 3;
        int ocL = r & 63;  r >>= 6;
        int o   = r & 3;   r >>= 2;               // ic octet
        int tap = r % 9;
        int g   = r / 9;
        int ic  = o * 8 + e;
        wbf[j] = (__bf16)wgt[((g * OPG + ocL) * CPG + ic) * 9 + tap];
    }
}

// ---------- main: zero-tail geometry (TH=4, 128 thr, 7 blocks/CU exact) ----------
// 1792 blocks = 7 x 256 CUs exactly — no drain tail. 2 waves/block, each wave =
// one oc-pair over all 14 tiles. Stage 6 padded rows (22 chunks) via gload_lds.
// Swapped-operand MFMA (lane=oc, regs=4 consecutive pixels) -> dwordx4 stores.
__global__ __launch_bounds__(128, 4) void conv_main(
    const __bf16* __restrict__ xt, const __bf16* __restrict__ wbf,
    const float* __restrict__ gctx, float* __restrict__ out)
{
    __shared__ __align__(16) __bf16 x_lds[LDS_B / 2];   // 22528 B

    const int ht  = blockIdx.x;   // 0..13 (4-row strip)
    const int g   = blockIdx.y;   // 0..3
    const int n   = blockIdx.z;   // 0..31
    const int tid = threadIdx.x;  // 0..127 (2 waves)
    const int h0  = ht * TH;

    const int wv   = tid >> 6;       // 0..1 = oc-pair
    const int lane = tid & 63;
    const int l15  = lane & 15;      // oc within tile / A-row pixel
    const int kh4  = lane >> 4;      // ic octet / D pixel-quad group
    const int p2   = wv * 2;         // oc-tile pair base (0 or 2)

    // ---- stage 6 padded rows h0..h0+5 FIRST ----
    {
        const char* sbase = (const char*)(xt + ((size_t)(n * GROUPS + g) * HP + h0) * ROWB);
        char* lbase = (char*)&x_lds[0];
        #pragma unroll
        for (int ch = 0; ch < SCHUNKS / 2; ++ch) {        // 11 insts per wave
            int c2 = ch * 2 + wv;                          // wave-uniform dest base
            gload16(sbase + c2 * 1024 + lane * 16, lbase + c2 * 1024);
        }
        // (last chunk's 256B slack reads inside d_ws [xt|gctx|wbf], never consumed)
    }

    // ---- w-frags from pre-permuted global; PIN so compiler can't sink ----
    u32x4 a[2][9];
    {
        const __bf16* wgb = wbf + (size_t)g * (9 * 4 * OPG * 8);
        #pragma unroll
        for (int i = 0; i < 2; ++i)
            #pragma unroll
            for (int tap = 0; tap < 9; ++tap)
                a[i][tap] = *(const u32x4*)&wgb[(((tap * 4 + kh4) * OPG) + (p2 + i) * 16 + l15) * 8];
    }
    #pragma unroll
    for (int i = 0; i < 2; ++i)
        #pragma unroll
        for (int tap = 0; tap < 9; ++tap)
            asm volatile("" : "+v"(a[i][tap]));

    float ctxv[2];
    #pragma unroll
    for (int i = 0; i < 2; ++i)
        ctxv[i] = gctx[n * COUT + g * OPG + (p2 + i) * 16 + l15];

    __syncthreads();   // 2-wave barrier

    float* outb0 = out + ((size_t)n * COUT + g * OPG + p2 * 16 + l15) * HW_ + h0 * W_;
    float* outb1 = outb0 + (size_t)16 * HW_;

    #pragma unroll 1
    for (int t = 0; t < NT; ++t) {
        int p  = t * 16 + l15;           // A-row pixel for LDS read
        int pr = p / W_;
        int pc = p - pr * W_;
        f32x4 acc0 = {ctxv[0], ctxv[0], ctxv[0], ctxv[0]};   // ctx as C-init
        f32x4 acc1 = {ctxv[1], ctxv[1], ctxv[1], ctxv[1]};
        #pragma unroll
        for (int kh = 0; kh < 3; ++kh) {
            #pragma unroll
            for (int kw = 0; kw < 3; ++kw) {
                int pix = pc + kw;
                int idx = (pr + kh) * ROWB + pix * CPG + ((kh4 ^ ((pix >> 1) & 3)) << 3);
                const bf16x8 b = *(const bf16x8*)&x_lds[idx];
                // swapped operands: D[m=pixel][n=oc]
                acc0 = __builtin_amdgcn_mfma_f32_16x16x32_bf16(
                           b, __builtin_bit_cast(bf16x8, a[0][kh * 3 + kw]), acc0, 0, 0, 0);
                acc1 = __builtin_amdgcn_mfma_f32_16x16x32_bf16(
                           b, __builtin_bit_cast(bf16x8, a[1][kh * 3 + kw]), acc1, 0, 0, 0);
            }
        }
        // lane writes 4 consecutive pixels for its oc in each oc-tile
        int p0 = t * 16 + kh4 * 4;
        *(f32x4*)&outb0[p0] = acc0;
        *(f32x4*)&outb1[p0] = acc1;
    }
}

// ---------- fallback (R2 structure) if workspace can't hold xt ----------
__global__ void ctx_kernel_fb(const float* __restrict__ c, const float* __restrict__ bias,
                              const float* __restrict__ cw, float* __restrict__ gctx) {
    const int n  = blockIdx.x;
    const int oc = threadIdx.x;
    const float* cn  = c  + n * CDIM;
    const float* cwo = cw + oc * CDIM;
    float s = bias[oc];
    #pragma unroll
    for (int d = 0; d < CDIM; ++d) s += cn[d] * cwo[d];
    gctx[n * COUT + oc] = s;
}
__global__ void wconv_kernel_fb(const float* __restrict__ wgt, __bf16* __restrict__ wbf) {
    int j = blockIdx.x * 256 + threadIdx.x;
    int e   = j & 7;
    int r   = j >> 3;
    int ocL = r & 63;  r >>= 6;
    int o   = r & 3;   r >>= 2;
    int tap = r % 9;
    int g   = r / 9;
    int ic  = o * 8 + e;
    wbf[j] = (__bf16)wgt[((g * OPG + ocL) * CPG + ic) * 9 + tap];
}
__global__ __launch_bounds__(512, 4) void ctx_conv_fb(
    const float* __restrict__ x, const __bf16* __restrict__ wbf,
    const float* __restrict__ gctx, float* __restrict__ out)
{
    __shared__ __align__(16) __bf16 x_lds[XPLANE][CPG];
    const int ht  = blockIdx.x;
    const int g   = blockIdx.y;
    const int n   = blockIdx.z;
    const int tid = threadIdx.x;
    const int h0  = ht * FB_TH;
    const int wv   = tid >> 6;
    const int lane = tid & 63;
    const int l15  = lane & 15;
    const int kh4  = lane >> 4;
    const int p2   = (wv & 1) * 2;
    const int pq   = wv >> 1;

    bf16x8 a[2][9];
    {
        const __bf16* wgb = wbf + (size_t)g * (9 * 4 * OPG * 8);
        #pragma unroll
        for (int i = 0; i < 2; ++i)
            #pragma unroll
            for (int tap = 0; tap < 9; ++tap)
                a[i][tap] = *(const bf16x8*)&wgb[(((tap * 4 + kh4) * OPG) + (p2 + i) * 16 + l15) * 8];
    }
    float ctxv[2][4];
    #pragma unroll
    for (int i = 0; i < 2; ++i)
        #pragma unroll
        for (int r = 0; r < 4; ++r)
            ctxv[i][r] = gctx[n * COUT + g * OPG + (p2 + i) * 16 + kh4 * 4 + r];
    {
        const float* xg = x + ((size_t)n * CIN + g * CPG) * HW_;
        for (int j = tid; j < 4 * XPLANE; j += 512) {
            int pix = j >> 2;
            int oct = j & 3;
            int hr = pix / HALO_C;
            int wc = pix - hr * HALO_C;
            int hg  = h0 - 1 + hr;
            int wg2 = wc - 1;
            bool valid = ((unsigned)hg < (unsigned)H_) && ((unsigned)wg2 < (unsigned)W_);
            const float* src = xg + (size_t)(oct * 8) * HW_ + hg * W_ + wg2;
            bf16x8 v;
            #pragma unroll
            for (int e = 0; e < 8; ++e)
                v[e] = (__bf16)(valid ? src[(size_t)e * HW_] : 0.f);
            *(bf16x8*)&x_lds[pix][oct * 8] = v;
        }
    }
    __syncthreads();
    float* outb = out + ((size_t)n * COUT + g * OPG + p2 * 16 + kh4 * 4) * HW_ + h0 * W_;
    #pragma unroll 1
    for (int t = pq * 7; t < pq * 7 + 7; ++t) {
        int p  = t * 16 + l15;
        int pr = p / W_;
        int pc = p - pr * W_;
        f32x4 acc0 = {0.f, 0.f, 0.f, 0.f};
        f32x4 acc1 = {0.f, 0.f, 0.f, 0.f};
        #pragma unroll
        for (int kh = 0; kh < 3; ++kh) {
            #pragma unroll
            for (int kw = 0; kw < 3; ++kw) {
                const bf16x8 b = *(const bf16x8*)&x_lds[(pr + kh) * HALO_C + (pc + kw)][kh4 * 8];
                acc0 = __builtin_amdgcn_mfma_f32_16x16x32_bf16(a[0][kh * 3 + kw], b, acc0, 0, 0, 0);
                acc1 = __builtin_amdgcn_mfma_f32_16x16x32_bf16(a[1][kh * 3 + kw], b, acc1, 0, 0, 0);
            }
        }
        #pragma unroll
        for (int r = 0; r < 4; ++r)
            outb[(size_t)r * HW_ + p] = acc0[r] + ctxv[0][r];
        #pragma unroll
        for (int r = 0; r < 4; ++r)
            outb[(size_t)(16 + r) * HW_ + p] = acc1[r] + ctxv[1][r];
    }
}

extern "C" void kernel_launch(void* const* d_in, const int* in_sizes, int n_in,
                              void* d_out, int out_size, void* d_ws, size_t ws_size,
                              hipStream_t stream) {
    const float* x    = (const float*)d_in[0];
    const float* c    = (const float*)d_in[1];
    const float* wgt  = (const float*)d_in[2];
    const float* bias = (const float*)d_in[3];
    const float* cw   = (const float*)d_in[4];
    float* out = (float*)d_out;

    const size_t XT_BYTES   = (size_t)N_ * GROUPS * HP * HP * CPG * 2;   // 27,557,888
    const size_t GCTX_BYTES = (size_t)N_ * COUT * 4;                     // 32,768
    const size_t WBF_BYTES  = (size_t)COUT * CPG * 9 * 2;                // 147,456
    const size_t NEEDED     = XT_BYTES + GCTX_BYTES + WBF_BYTES;

    if (ws_size >= NEEDED) {
        __bf16* xt   = (__bf16*)d_ws;
        float*  gctx = (float*)((char*)d_ws + XT_BYTES);
        __bf16* wbf  = (__bf16*)((char*)d_ws + XT_BYTES + GCTX_BYTES);

        const int nxpose = HP * GROUPS * N_;                       // 7424
        const int npre   = nxpose + N_ + (COUT * CPG * 9) / 256;   // +32 +36
        pre_kernel<<<dim3(npre), 256, 0, stream>>>(x, c, wgt, bias, cw, xt, gctx, wbf);

        dim3 grid(H_ / TH, GROUPS, N_);   // (14, 4, 32) = 1792 blocks x 128 thr
        conv_main<<<grid, 128, 0, stream>>>(xt, wbf, gctx, out);
    } else {
        float*  gctx = (float*)d_ws;
        __bf16* wbf  = (__bf16*)((char*)d_ws + 32768);
        ctx_kernel_fb<<<dim3(N_), 256, 0, stream>>>(c, bias, cw, gctx);
        wconv_kernel_fb<<<dim3((COUT * CPG * 9) / 256), 256, 0, stream>>>(wgt, wbf);
        dim3 grid(H_ / FB_TH, GROUPS, N_);
        ctx_conv_fb<<<grid, 512, 0, stream>>>(x, wbf, gctx, out);
    }
}

// Round 18
// 48.737 us; speedup vs baseline: 1.0102x; 1.0102x over previous
//
#include <hip/hip_runtime.h>

#define N_    32
#define CIN   128
#define H_    56
#define W_    56
#define HW_   (H_ * W_)
#define COUT  256
#define GROUPS 4
#define CPG   32      // in-channels per group
#define OPG   64      // out-channels per group
#define CDIM  64
#define HP    58      // padded spatial dim (1-px zero halo each side)

#define TH    8               // output rows per block
#define NPIX  (TH * W_)       // 448
#define NT32  (NPIX / 32)     // 14 pixel tiles of 32 (7 per wave)

#define ROWB  (HP * CPG)      // bf16 per padded row = 1856 (3712 B)
#define ROW4  232             // dwordx4 per row
#define STRIP_CHUNKS 37       // ceil(10*3712 / 1024)

// fallback-path tile geometry (R2 kernel)
#define FB_TH   8
#define HALO_R (FB_TH + 2)
#define HALO_C (W_ + 2)
#define XPLANE (HALO_R * HALO_C)

typedef __bf16 bf16x8 __attribute__((ext_vector_type(8)));
typedef __bf16 bf16x2 __attribute__((ext_vector_type(2)));
typedef float  f32x4  __attribute__((ext_vector_type(4)));
typedef float  f32x16 __attribute__((ext_vector_type(16)));
typedef unsigned int u32x4 __attribute__((ext_vector_type(4)));

__device__ __forceinline__ void gload16(const void* g, void* l) {
    __builtin_amdgcn_global_load_lds((const __attribute__((address_space(1))) void*)g,
                                     (__attribute__((address_space(3))) void*)l, 16, 0, 0);
}

__device__ __forceinline__ uint packbf2(float a, float b) {
    bf16x2 v; v[0] = (__bf16)a; v[1] = (__bf16)b;
    return __builtin_bit_cast(unsigned int, v);
}

// ---------- merged pre-kernel (R13, vectorized): xpose (7424) + ctx (32) + wconv (36) ----------
// xt layout: [n][g][58 rows][58 pixels][4 slots][8 ic] bf16; octet o of pixel pix
// stored at slot o ^ ((pix>>1)&3). float4 reads, dwordx4 writes.
__global__ __launch_bounds__(256) void pre_kernel(
    const float* __restrict__ x, const float* __restrict__ c,
    const float* __restrict__ wgt, const float* __restrict__ bias,
    const float* __restrict__ cw,
    __bf16* __restrict__ xt, float* __restrict__ gctx, __bf16* __restrict__ wbf)
{
    const int bid = blockIdx.x;
    const int tid = threadIdx.x;

    if (bid < HP * GROUPS * N_) {                 // ---- xpose (one padded row) ----
        const int hh = bid % HP;
        const int g  = (bid / HP) & (GROUPS - 1);
        const int n  = bid / (HP * GROUPS);
        u32x4* drow4 = (u32x4*)(xt + ((size_t)(n * GROUPS + g) * HP + hh) * ROWB);
        const int h = hh - 1;
        if ((unsigned)h >= (unsigned)H_) {        // top/bottom halo row: zeros
            if (tid < ROW4) drow4[tid] = (u32x4){0u, 0u, 0u, 0u};
            return;
        }
        __shared__ float t[CPG][57];              // [ic][w]; pad 57
        const float* src = x + ((size_t)(n * CIN + g * CPG) * H_ + h) * W_;
        for (int j = tid; j < CPG * (W_ / 4); j += 256) {
            int ic = j / 14, q = j - ic * 14;
            f32x4 v = *(const f32x4*)&src[(size_t)ic * HW_ + q * 4];
            #pragma unroll
            for (int k = 0; k < 4; ++k) t[ic][q * 4 + k] = v[k];
        }
        __syncthreads();
        if (tid < ROW4) {
            int pix = tid >> 2;
            int oct = (tid & 3) ^ ((pix >> 1) & 3);
            int w = pix - 1;
            u32x4 o4 = {0u, 0u, 0u, 0u};
            if ((unsigned)w < (unsigned)W_) {
                #pragma unroll
                for (int dd = 0; dd < 4; ++dd)
                    o4[dd] = packbf2(t[oct * 8 + dd * 2][w], t[oct * 8 + dd * 2 + 1][w]);
            }
            drow4[tid] = o4;
        }
    } else if (bid < HP * GROUPS * N_ + N_) {     // ---- ctx ----
        const int n  = bid - HP * GROUPS * N_;
        const int oc = tid;
        const float* cn  = c  + n * CDIM;
        const float* cwo = cw + oc * CDIM;
        float s = bias[oc];
        #pragma unroll
        for (int d = 0; d < CDIM; ++d) s += cn[d] * cwo[d];
        gctx[n * COUT + oc] = s;
    } else {                                      // ---- wconv: bf16 [g][tap][oct][ocL][8] ----
        int j = (bid - (HP * GROUPS * N_ + N_)) * 256 + tid;
        int e   = j & 7;
        int r   = j >> 3;
        int ocL = r & 63;  r >>= 6;
        int o   = r & 3;   r >>= 2;               // ic octet
        int tap = r % 9;
        int g   = r / 9;
        int ic  = o * 8 + e;
        wbf[j] = (__bf16)wgt[((g * OPG + ocL) * CPG + ic) * 9 + tap];
    }
}

// ---------- main: 32x32x16 MFMA — half the ds_read + MFMA instruction count ----------
// 896 blocks x 128 thr (2 waves), 4 blocks/CU -> ALL blocks co-resident. Wave =
// pixel-half (7 tiles of 32 px) x BOTH 32-oc tiles. Per (tap, kslice): one shared
// ds_read_b128 feeds 2 MFMAs. A: pixel=l&31, ic=ks*16+(l>>5)*8+e. B(w): oc=l&31,
// same k. D: col=oc=l&31, row(px)=(reg&3)+8*(reg>>2)+4*(l>>5) [m74/m101 verified].
__global__ __attribute__((amdgpu_flat_work_group_size(128, 128), amdgpu_waves_per_eu(2, 2)))
void conv_main(
    const __bf16* __restrict__ xt, const __bf16* __restrict__ wbf,
    const float* __restrict__ gctx, float* __restrict__ out)
{
    __shared__ __align__(16) __bf16 x_lds[(STRIP_CHUNKS * 1024) / 2];   // 37888 B

    const int ht  = blockIdx.x;   // 0..6  (8-row strip)
    const int g   = blockIdx.y;   // 0..3
    const int n   = blockIdx.z;   // 0..31
    const int tid = threadIdx.x;  // 0..127 (2 waves)
    const int h0  = ht * TH;

    const int wv   = tid >> 6;       // 0..1 = pixel half
    const int lane = tid & 63;
    const int l31  = lane & 31;      // A pixel / D oc within 32-tile
    const int lh   = lane >> 5;      // k-octet half / D pixel-quad shift

    // ---- stage strip rows h0..h0+9 FIRST ----
    {
        const char* sbase = (const char*)(xt + ((size_t)(n * GROUPS + g) * HP + h0) * ROWB);
        char* lbase = (char*)&x_lds[0];
        for (int ch = wv; ch < STRIP_CHUNKS; ch += 2)     // wave-uniform dest base
            gload16(sbase + ch * 1024 + lane * 16, lbase + ch * 1024);
    }

    // ---- w-frags: a[ocT][tap][ks]; ic-octet = ks*2+lh; PIN all 36 (144 VGPR) ----
    u32x4 a[2][9][2];
    {
        const __bf16* wgb = wbf + (size_t)g * (9 * 4 * OPG * 8);
        #pragma unroll
        for (int i = 0; i < 2; ++i)
            #pragma unroll
            for (int tap = 0; tap < 9; ++tap)
                #pragma unroll
                for (int ks = 0; ks < 2; ++ks)
                    a[i][tap][ks] = *(const u32x4*)
                        &wgb[(((tap * 4 + (ks * 2 + lh)) * OPG) + i * 32 + l31) * 8];
    }
    #pragma unroll
    for (int i = 0; i < 2; ++i)
        #pragma unroll
        for (int tap = 0; tap < 9; ++tap)
            #pragma unroll
            for (int ks = 0; ks < 2; ++ks)
                asm volatile("" : "+v"(a[i][tap][ks]));

    float ctxv[2];
    #pragma unroll
    for (int i = 0; i < 2; ++i)
        ctxv[i] = gctx[n * COUT + g * OPG + i * 32 + l31];

    __syncthreads();   // 2-wave barrier

    // lane's output rows: oc = g*OPG + i*32 + l31
    float* outr0 = out + ((size_t)n * COUT + g * OPG + l31) * HW_ + h0 * W_;
    float* outr1 = outr0 + (size_t)32 * HW_;

    #pragma unroll 1
    for (int t = wv * (NT32 / 2); t < wv * (NT32 / 2) + NT32 / 2; ++t) {
        int p  = t * 32 + l31;           // A-row pixel for LDS read
        int pr = p / W_;
        int pc = p - pr * W_;
        f32x16 acc0, acc1;
        #pragma unroll
        for (int r = 0; r < 16; ++r) { acc0[r] = ctxv[0]; acc1[r] = ctxv[1]; }
        #pragma unroll
        for (int kh = 0; kh < 3; ++kh) {
            #pragma unroll
            for (int kw = 0; kw < 3; ++kw) {
                int pix = pc + kw;
                #pragma unroll
                for (int ks = 0; ks < 2; ++ks) {
                    int oct = ks * 2 + lh;
                    int idx = (pr + kh) * ROWB + pix * CPG
                            + ((oct ^ ((pix >> 1) & 3)) << 3);
                    const bf16x8 b = *(const bf16x8*)&x_lds[idx];
                    // swapped operands: D[m=pixel][n=oc]
                    acc0 = __builtin_amdgcn_mfma_f32_32x32x16_bf16(
                               b, __builtin_bit_cast(bf16x8, a[0][kh * 3 + kw][ks]), acc0, 0, 0, 0);
                    acc1 = __builtin_amdgcn_mfma_f32_32x32x16_bf16(
                               b, __builtin_bit_cast(bf16x8, a[1][kh * 3 + kw][ks]), acc1, 0, 0, 0);
                }
            }
        }
        // stores: reg-quad q holds pixels t*32 + 8q + 4*lh + 0..3 of lane's oc row
        #pragma unroll
        for (int q = 0; q < 4; ++q) {
            int p0 = t * 32 + 8 * q + 4 * lh;
            f32x4 v0 = {acc0[4 * q], acc0[4 * q + 1], acc0[4 * q + 2], acc0[4 * q + 3]};
            f32x4 v1 = {acc1[4 * q], acc1[4 * q + 1], acc1[4 * q + 2], acc1[4 * q + 3]};
            *(f32x4*)&outr0[p0] = v0;
            *(f32x4*)&outr1[p0] = v1;
        }
    }
}

// ---------- fallback (R2 structure) if workspace can't hold xt ----------
__global__ void ctx_kernel_fb(const float* __restrict__ c, const float* __restrict__ bias,
                              const float* __restrict__ cw, float* __restrict__ gctx) {
    const int n  = blockIdx.x;
    const int oc = threadIdx.x;
    const float* cn  = c  + n * CDIM;
    const float* cwo = cw + oc * CDIM;
    float s = bias[oc];
    #pragma unroll
    for (int d = 0; d < CDIM; ++d) s += cn[d] * cwo[d];
    gctx[n * COUT + oc] = s;
}
__global__ void wconv_kernel_fb(const float* __restrict__ wgt, __bf16* __restrict__ wbf) {
    int j = blockIdx.x * 256 + threadIdx.x;
    int e   = j & 7;
    int r   = j >> 3;
    int ocL = r & 63;  r >>= 6;
    int o   = r & 3;   r >>= 2;
    int tap = r % 9;
    int g   = r / 9;
    int ic  = o * 8 + e;
    wbf[j] = (__bf16)wgt[((g * OPG + ocL) * CPG + ic) * 9 + tap];
}
__global__ __launch_bounds__(512, 4) void ctx_conv_fb(
    const float* __restrict__ x, const __bf16* __restrict__ wbf,
    const float* __restrict__ gctx, float* __restrict__ out)
{
    __shared__ __align__(16) __bf16 x_lds[XPLANE][CPG];
    const int ht  = blockIdx.x;
    const int g   = blockIdx.y;
    const int n   = blockIdx.z;
    const int tid = threadIdx.x;
    const int h0  = ht * FB_TH;
    const int wv   = tid >> 6;
    const int lane = tid & 63;
    const int l15  = lane & 15;
    const int kh4  = lane >> 4;
    const int p2   = (wv & 1) * 2;
    const int pq   = wv >> 1;

    bf16x8 a[2][9];
    {
        const __bf16* wgb = wbf + (size_t)g * (9 * 4 * OPG * 8);
        #pragma unroll
        for (int i = 0; i < 2; ++i)
            #pragma unroll
            for (int tap = 0; tap < 9; ++tap)
                a[i][tap] = *(const bf16x8*)&wgb[(((tap * 4 + kh4) * OPG) + (p2 + i) * 16 + l15) * 8];
    }
    float ctxv[2][4];
    #pragma unroll
    for (int i = 0; i < 2; ++i)
        #pragma unroll
        for (int r = 0; r < 4; ++r)
            ctxv[i][r] = gctx[n * COUT + g * OPG + (p2 + i) * 16 + kh4 * 4 + r];
    {
        const float* xg = x + ((size_t)n * CIN + g * CPG) * HW_;
        for (int j = tid; j < 4 * XPLANE; j += 512) {
            int pix = j >> 2;
            int oct = j & 3;
            int hr = pix / HALO_C;
            int wc = pix - hr * HALO_C;
            int hg  = h0 - 1 + hr;
            int wg2 = wc - 1;
            bool valid = ((unsigned)hg < (unsigned)H_) && ((unsigned)wg2 < (unsigned)W_);
            const float* src = xg + (size_t)(oct * 8) * HW_ + hg * W_ + wg2;
            bf16x8 v;
            #pragma unroll
            for (int e = 0; e < 8; ++e)
                v[e] = (__bf16)(valid ? src[(size_t)e * HW_] : 0.f);
            *(bf16x8*)&x_lds[pix][oct * 8] = v;
        }
    }
    __syncthreads();
    float* outb = out + ((size_t)n * COUT + g * OPG + p2 * 16 + kh4 * 4) * HW_ + h0 * W_;
    #pragma unroll 1
    for (int t = pq * 7; t < pq * 7 + 7; ++t) {
        int p  = t * 16 + l15;
        int pr = p / W_;
        int pc = p - pr * W_;
        f32x4 acc0 = {0.f, 0.f, 0.f, 0.f};
        f32x4 acc1 = {0.f, 0.f, 0.f, 0.f};
        #pragma unroll
        for (int kh = 0; kh < 3; ++kh) {
            #pragma unroll
            for (int kw = 0; kw < 3; ++kw) {
                const bf16x8 b = *(const bf16x8*)&x_lds[(pr + kh) * HALO_C + (pc + kw)][kh4 * 8];
                acc0 = __builtin_amdgcn_mfma_f32_16x16x32_bf16(a[0][kh * 3 + kw], b, acc0, 0, 0, 0);
                acc1 = __builtin_amdgcn_mfma_f32_16x16x32_bf16(a[1][kh * 3 + kw], b, acc1, 0, 0, 0);
            }
        }
        #pragma unroll
        for (int r = 0; r < 4; ++r)
            outb[(size_t)r * HW_ + p] = acc0[r] + ctxv[0][r];
        #pragma unroll
        for (int r = 0; r < 4; ++r)
            outb[(size_t)(16 + r) * HW_ + p] = acc1[r] + ctxv[1][r];
    }
}

extern "C" void kernel_launch(void* const* d_in, const int* in_sizes, int n_in,
                              void* d_out, int out_size, void* d_ws, size_t ws_size,
                              hipStream_t stream) {
    const float* x    = (const float*)d_in[0];
    const float* c    = (const float*)d_in[1];
    const float* wgt  = (const float*)d_in[2];
    const float* bias = (const float*)d_in[3];
    const float* cw   = (const float*)d_in[4];
    float* out = (float*)d_out;

    const size_t XT_BYTES   = (size_t)N_ * GROUPS * HP * HP * CPG * 2;   // 27,557,888
    const size_t GCTX_BYTES = (size_t)N_ * COUT * 4;                     // 32,768
    const size_t WBF_BYTES  = (size_t)COUT * CPG * 9 * 2;                // 147,456
    const size_t NEEDED     = XT_BYTES + GCTX_BYTES + WBF_BYTES;

    if (ws_size >= NEEDED) {
        __bf16* xt   = (__bf16*)d_ws;
        float*  gctx = (float*)((char*)d_ws + XT_BYTES);
        __bf16* wbf  = (__bf16*)((char*)d_ws + XT_BYTES + GCTX_BYTES);

        const int nxpose = HP * GROUPS * N_;                       // 7424
        const int npre   = nxpose + N_ + (COUT * CPG * 9) / 256;   // +32 +36
        pre_kernel<<<dim3(npre), 256, 0, stream>>>(x, c, wgt, bias, cw, xt, gctx, wbf);

        dim3 grid(H_ / TH, GROUPS, N_);   // (7, 4, 32) = 896 blocks x 128 thr
        conv_main<<<grid, 128, 0, stream>>>(xt, wbf, gctx, out);
    } else {
        float*  gctx = (float*)d_ws;
        __bf16* wbf  = (__bf16*)((char*)d_ws + 32768);
        ctx_kernel_fb<<<dim3(N_), 256, 0, stream>>>(c, bias, cw, gctx);
        wconv_kernel_fb<<<dim3((COUT * CPG * 9) / 256), 256, 0, stream>>>(wgt, wbf);
        dim3 grid(H_ / FB_TH, GROUPS, N_);
        ctx_conv_fb<<<grid, 512, 0, stream>>>(x, wbf, gctx, out);
    }
}

// Round 19
// 47.640 us; speedup vs baseline: 1.0335x; 1.0230x over previous
//
#include <hip/hip_runtime.h>

#define N_    32
#define CIN   128
#define H_    56
#define W_    56
#define HW_   (H_ * W_)
#define COUT  256
#define GROUPS 4
#define CPG   32      // in-channels per group
#define OPG   64      // out-channels per group
#define CDIM  64
#define HP    58      // padded spatial dim (1-px zero halo each side)

#define TH    8               // output rows per block
#define NPIX  (TH * W_)       // 448
#define NT    (NPIX / 16)     // 28 pixel tiles (14 per wave-half)

#define ROWB  (HP * CPG)      // bf16 per padded row = 1856 (3712 B)
#define ROW4  232             // dwordx4 per row
#define NXP   29              // row-pairs per (n,g) in pre
#define STRIP_CHUNKS 37       // ceil(10*3712 / 1024)

// fallback-path tile geometry (R2 kernel)
#define FB_TH   8
#define HALO_R (FB_TH + 2)
#define HALO_C (W_ + 2)
#define XPLANE (HALO_R * HALO_C)

typedef __bf16 bf16x8 __attribute__((ext_vector_type(8)));
typedef __bf16 bf16x2 __attribute__((ext_vector_type(2)));
typedef float  f32x4  __attribute__((ext_vector_type(4)));
typedef unsigned int u32x4 __attribute__((ext_vector_type(4)));

__device__ __forceinline__ void gload16(const void* g, void* l) {
    __builtin_amdgcn_global_load_lds((const __attribute__((address_space(1))) void*)g,
                                     (__attribute__((address_space(3))) void*)l, 16, 0, 0);
}

__device__ __forceinline__ uint packbf2(float a, float b) {
    bf16x2 v; v[0] = (__bf16)a; v[1] = (__bf16)b;
    return __builtin_bit_cast(unsigned int, v);
}

// ---------- merged pre-kernel: xpose-pairs (3712) + ctx (32) + wconv (36) ----------
// xt layout: [n][g][58 rows][58 pixels][4 slots][8 ic] bf16; octet o of pixel pix
// stored at slot o ^ ((pix>>1)&3). Bounce LDS vectorized: t[2][32][60] fp32 —
// 240B row stride -> ds_write_b128 on load side (0.25 lane-ops/elem vs 1), and
// adjacent-row pair reads 60 dwords apart fuse to ds_read2_b32 (0.5/elem vs 1).
// 2 padded rows per block: half the blocks, one __syncthreads.
__global__ __launch_bounds__(256) void pre_kernel(
    const float* __restrict__ x, const float* __restrict__ c,
    const float* __restrict__ wgt, const float* __restrict__ bias,
    const float* __restrict__ cw,
    __bf16* __restrict__ xt, float* __restrict__ gctx, __bf16* __restrict__ wbf)
{
    const int bid = blockIdx.x;
    const int tid = threadIdx.x;

    if (bid < NXP * GROUPS * N_) {                // ---- xpose: padded rows 2p, 2p+1 ----
        const int pp = bid % NXP;
        const int g  = (bid / NXP) & (GROUPS - 1);
        const int n  = bid / (NXP * GROUPS);
        __shared__ float t[2][CPG][60];           // 15360 B; 240B rows (16B-aligned)
        const float* xbase = x + (size_t)(n * CIN + g * CPG) * HW_;
        // load: 896 f32x4 jobs, b128 LDS writes
        for (int j = tid; j < 2 * CPG * 14; j += 256) {
            int rr = j / (CPG * 14);
            int k  = j - rr * (CPG * 14);
            int ic = k / 14, q = k - ic * 14;
            int h  = 2 * pp + rr - 1;             // global row for padded hh=2pp+rr
            if ((unsigned)h < (unsigned)H_) {
                f32x4 v = *(const f32x4*)&xbase[(size_t)ic * HW_ + h * W_ + q * 4];
                *(f32x4*)&t[rr][ic][q * 4] = v;
            }
        }
        __syncthreads();
        // store: 464 dwordx4 jobs; word dd packs (ic=oct*8+2dd, ic+1) at w
        u32x4* dbase = (u32x4*)(xt + ((size_t)(n * GROUPS + g) * HP + 2 * pp) * ROWB);
        for (int j = tid; j < 2 * ROW4; j += 256) {
            int rr  = j / ROW4;
            int t2  = j - rr * ROW4;
            int pix = t2 >> 2;
            int oct = (t2 & 3) ^ ((pix >> 1) & 3);
            int w   = pix - 1;
            int h   = 2 * pp + rr - 1;
            u32x4 o4 = {0u, 0u, 0u, 0u};
            if ((unsigned)w < (unsigned)W_ && (unsigned)h < (unsigned)H_) {
                #pragma unroll
                for (int dd = 0; dd < 4; ++dd)
                    o4[dd] = packbf2(t[rr][oct * 8 + dd * 2][w],
                                     t[rr][oct * 8 + dd * 2 + 1][w]);
            }
            dbase[(size_t)rr * ROW4 + t2] = o4;
        }
    } else if (bid < NXP * GROUPS * N_ + N_) {    // ---- ctx ----
        const int n  = bid - NXP * GROUPS * N_;
        const int oc = tid;
        const float* cn  = c  + n * CDIM;
        const float* cwo = cw + oc * CDIM;
        float s = bias[oc];
        #pragma unroll
        for (int d = 0; d < CDIM; ++d) s += cn[d] * cwo[d];
        gctx[n * COUT + oc] = s;
    } else {                                      // ---- wconv: bf16 [g][tap][oct][ocL][8] ----
        int j = (bid - (NXP * GROUPS * N_ + N_)) * 256 + tid;
        int e   = j & 7;
        int r   = j >> 3;
        int ocL = r & 63;  r >>= 6;
        int o   = r & 3;   r >>= 2;               // ic octet
        int tap = r % 9;
        int g   = r / 9;
        int ic  = o * 8 + e;
        wbf[j] = (__bf16)wgt[((g * OPG + ocL) * CPG + ic) * 9 + tap];
    }
}

// ---------- main kernel: R13 champion verbatim ----------
__global__ __launch_bounds__(256, 4) void conv_main(
    const __bf16* __restrict__ xt, const __bf16* __restrict__ wbf,
    const float* __restrict__ gctx, float* __restrict__ out)
{
    __shared__ __align__(16) __bf16 x_lds[(STRIP_CHUNKS * 1024) / 2];   // 37888 B

    const int ht  = blockIdx.x;   // 0..6  (8-row strip)
    const int g   = blockIdx.y;   // 0..3
    const int n   = blockIdx.z;   // 0..31
    const int tid = threadIdx.x;  // 0..255 (4 waves)
    const int h0  = ht * TH;

    const int wv   = tid >> 6;       // 0..3
    const int lane = tid & 63;
    const int l15  = lane & 15;
    const int kh4  = lane >> 4;      // ic octet / D pixel-quad group
    const int p2   = (wv & 1) * 2;   // oc-tile pair base (0 or 2)
    const int ph   = wv >> 1;        // pixel half (14 tiles each)

    // ---- stage strip rows h0..h0+9 FIRST ----
    {
        const char* sbase = (const char*)(xt + ((size_t)(n * GROUPS + g) * HP + h0) * ROWB);
        char* lbase = (char*)&x_lds[0];
        for (int ch = wv; ch < STRIP_CHUNKS; ch += 4)     // wave-uniform dest base
            gload16(sbase + ch * 1024 + lane * 16, lbase + ch * 1024);
    }

    // ---- w-frags from pre-permuted global; PIN so compiler can't sink ----
    u32x4 a[2][9];
    {
        const __bf16* wgb = wbf + (size_t)g * (9 * 4 * OPG * 8);
        #pragma unroll
        for (int i = 0; i < 2; ++i)
            #pragma unroll
            for (int tap = 0; tap < 9; ++tap)
                a[i][tap] = *(const u32x4*)&wgb[(((tap * 4 + kh4) * OPG) + (p2 + i) * 16 + l15) * 8];
    }
    #pragma unroll
    for (int i = 0; i < 2; ++i)
        #pragma unroll
        for (int tap = 0; tap < 9; ++tap)
            asm volatile("" : "+v"(a[i][tap]));

    float ctxv[2];
    #pragma unroll
    for (int i = 0; i < 2; ++i)
        ctxv[i] = gctx[n * COUT + g * OPG + (p2 + i) * 16 + l15];

    __syncthreads();

    float* outb0 = out + ((size_t)n * COUT + g * OPG + p2 * 16 + l15) * HW_ + h0 * W_;
    float* outb1 = outb0 + (size_t)16 * HW_;

    #pragma unroll 1
    for (int t = ph * 14; t < ph * 14 + 14; ++t) {
        int p  = t * 16 + l15;           // A-row pixel for LDS read
        int pr = p / W_;
        int pc = p - pr * W_;
        f32x4 acc0 = {ctxv[0], ctxv[0], ctxv[0], ctxv[0]};   // ctx as C-init
        f32x4 acc1 = {ctxv[1], ctxv[1], ctxv[1], ctxv[1]};
        #pragma unroll
        for (int kh = 0; kh < 3; ++kh) {
            #pragma unroll
            for (int kw = 0; kw < 3; ++kw) {
                int pix = pc + kw;
                int idx = (pr + kh) * ROWB + pix * CPG + ((kh4 ^ ((pix >> 1) & 3)) << 3);
                const bf16x8 b = *(const bf16x8*)&x_lds[idx];
                // swapped operands: D[m=pixel][n=oc]
                acc0 = __builtin_amdgcn_mfma_f32_16x16x32_bf16(
                           b, __builtin_bit_cast(bf16x8, a[0][kh * 3 + kw]), acc0, 0, 0, 0);
                acc1 = __builtin_amdgcn_mfma_f32_16x16x32_bf16(
                           b, __builtin_bit_cast(bf16x8, a[1][kh * 3 + kw]), acc1, 0, 0, 0);
            }
        }
        int p0 = t * 16 + kh4 * 4;
        *(f32x4*)&outb0[p0] = acc0;
        *(f32x4*)&outb1[p0] = acc1;
    }
}

// ---------- fallback (R2 structure) if workspace can't hold xt ----------
__global__ void ctx_kernel_fb(const float* __restrict__ c, const float* __restrict__ bias,
                              const float* __restrict__ cw, float* __restrict__ gctx) {
    const int n  = blockIdx.x;
    const int oc = threadIdx.x;
    const float* cn  = c  + n * CDIM;
    const float* cwo = cw + oc * CDIM;
    float s = bias[oc];
    #pragma unroll
    for (int d = 0; d < CDIM; ++d) s += cn[d] * cwo[d];
    gctx[n * COUT + oc] = s;
}
__global__ void wconv_kernel_fb(const float* __restrict__ wgt, __bf16* __restrict__ wbf) {
    int j = blockIdx.x * 256 + threadIdx.x;
    int e   = j & 7;
    int r   = j >> 3;
    int ocL = r & 63;  r >>= 6;
    int o   = r & 3;   r >>= 2;
    int tap = r % 9;
    int g   = r / 9;
    int ic  = o * 8 + e;
    wbf[j] = (__bf16)wgt[((g * OPG + ocL) * CPG + ic) * 9 + tap];
}
__global__ __launch_bounds__(512, 4) void ctx_conv_fb(
    const float* __restrict__ x, const __bf16* __restrict__ wbf,
    const float* __restrict__ gctx, float* __restrict__ out)
{
    __shared__ __align__(16) __bf16 x_lds[XPLANE][CPG];
    const int ht  = blockIdx.x;
    const int g   = blockIdx.y;
    const int n   = blockIdx.z;
    const int tid = threadIdx.x;
    const int h0  = ht * FB_TH;
    const int wv   = tid >> 6;
    const int lane = tid & 63;
    const int l15  = lane & 15;
    const int kh4  = lane >> 4;
    const int p2   = (wv & 1) * 2;
    const int pq   = wv >> 1;

    bf16x8 a[2][9];
    {
        const __bf16* wgb = wbf + (size_t)g * (9 * 4 * OPG * 8);
        #pragma unroll
        for (int i = 0; i < 2; ++i)
            #pragma unroll
            for (int tap = 0; tap < 9; ++tap)
                a[i][tap] = *(const bf16x8*)&wgb[(((tap * 4 + kh4) * OPG) + (p2 + i) * 16 + l15) * 8];
    }
    float ctxv[2][4];
    #pragma unroll
    for (int i = 0; i < 2; ++i)
        #pragma unroll
        for (int r = 0; r < 4; ++r)
            ctxv[i][r] = gctx[n * COUT + g * OPG + (p2 + i) * 16 + kh4 * 4 + r];
    {
        const float* xg = x + ((size_t)n * CIN + g * CPG) * HW_;
        for (int j = tid; j < 4 * XPLANE; j += 512) {
            int pix = j >> 2;
            int oct = j & 3;
            int hr = pix / HALO_C;
            int wc = pix - hr * HALO_C;
            int hg  = h0 - 1 + hr;
            int wg2 = wc - 1;
            bool valid = ((unsigned)hg < (unsigned)H_) && ((unsigned)wg2 < (unsigned)W_);
            const float* src = xg + (size_t)(oct * 8) * HW_ + hg * W_ + wg2;
            bf16x8 v;
            #pragma unroll
            for (int e = 0; e < 8; ++e)
                v[e] = (__bf16)(valid ? src[(size_t)e * HW_] : 0.f);
            *(bf16x8*)&x_lds[pix][oct * 8] = v;
        }
    }
    __syncthreads();
    float* outb = out + ((size_t)n * COUT + g * OPG + p2 * 16 + kh4 * 4) * HW_ + h0 * W_;
    #pragma unroll 1
    for (int t = pq * 7; t < pq * 7 + 7; ++t) {
        int p  = t * 16 + l15;
        int pr = p / W_;
        int pc = p - pr * W_;
        f32x4 acc0 = {0.f, 0.f, 0.f, 0.f};
        f32x4 acc1 = {0.f, 0.f, 0.f, 0.f};
        #pragma unroll
        for (int kh = 0; kh < 3; ++kh) {
            #pragma unroll
            for (int kw = 0; kw < 3; ++kw) {
                const bf16x8 b = *(const bf16x8*)&x_lds[(pr + kh) * HALO_C + (pc + kw)][kh4 * 8];
                acc0 = __builtin_amdgcn_mfma_f32_16x16x32_bf16(a[0][kh * 3 + kw], b, acc0, 0, 0, 0);
                acc1 = __builtin_amdgcn_mfma_f32_16x16x32_bf16(a[1][kh * 3 + kw], b, acc1, 0, 0, 0);
            }
        }
        #pragma unroll
        for (int r = 0; r < 4; ++r)
            outb[(size_t)r * HW_ + p] = acc0[r] + ctxv[0][r];
        #pragma unroll
        for (int r = 0; r < 4; ++r)
            outb[(size_t)(16 + r) * HW_ + p] = acc1[r] + ctxv[1][r];
    }
}

extern "C" void kernel_launch(void* const* d_in, const int* in_sizes, int n_in,
                              void* d_out, int out_size, void* d_ws, size_t ws_size,
                              hipStream_t stream) {
    const float* x    = (const float*)d_in[0];
    const float* c    = (const float*)d_in[1];
    const float* wgt  = (const float*)d_in[2];
    const float* bias = (const float*)d_in[3];
    const float* cw   = (const float*)d_in[4];
    float* out = (float*)d_out;

    const size_t XT_BYTES   = (size_t)N_ * GROUPS * HP * HP * CPG * 2;   // 27,557,888
    const size_t GCTX_BYTES = (size_t)N_ * COUT * 4;                     // 32,768
    const size_t WBF_BYTES  = (size_t)COUT * CPG * 9 * 2;                // 147,456
    const size_t NEEDED     = XT_BYTES + GCTX_BYTES + WBF_BYTES;

    if (ws_size >= NEEDED) {
        __bf16* xt   = (__bf16*)d_ws;
        float*  gctx = (float*)((char*)d_ws + XT_BYTES);
        __bf16* wbf  = (__bf16*)((char*)d_ws + XT_BYTES + GCTX_BYTES);

        const int nxpose = NXP * GROUPS * N_;                      // 3712
        const int npre   = nxpose + N_ + (COUT * CPG * 9) / 256;   // +32 +36 = 3780
        pre_kernel<<<dim3(npre), 256, 0, stream>>>(x, c, wgt, bias, cw, xt, gctx, wbf);

        dim3 grid(H_ / TH, GROUPS, N_);   // (7, 4, 32) = 896 blocks x 256 thr
        conv_main<<<grid, 256, 0, stream>>>(xt, wbf, gctx, out);
    } else {
        float*  gctx = (float*)d_ws;
        __bf16* wbf  = (__bf16*)((char*)d_ws + 32768);
        ctx_kernel_fb<<<dim3(N_), 256, 0, stream>>>(c, bias, cw, gctx);
        wconv_kernel_fb<<<dim3((COUT * CPG * 9) / 256), 256, 0, stream>>>(wgt, wbf);
        dim3 grid(H_ / FB_TH, GROUPS, N_);
        ctx_conv_fb<<<grid, 512, 0, stream>>>(x, wbf, gctx, out);
    }
}

// Round 20
// 47.303 us; speedup vs baseline: 1.0408x; 1.0071x over previous
//
#include <hip/hip_runtime.h>

#define N_    32
#define CIN   128
#define H_    56
#define W_    56
#define HW_   (H_ * W_)
#define COUT  256
#define GROUPS 4
#define CPG   32      // in-channels per group
#define OPG   64      // out-channels per group
#define CDIM  64
#define HP    58      // padded spatial dim (1-px zero halo each side)

#define TH    8               // output rows per block
#define NPIX  (TH * W_)       // 448
#define NT    (NPIX / 16)     // 28 pixel tiles (14 per wave-half)

#define ROWB  (HP * CPG)      // bf16 per padded row = 1856 (3712 B)
#define ROW4  232             // dwordx4 per row
#define STRIP_CHUNKS 37       // ceil(10*3712 / 1024)

// fallback-path tile geometry (R2 kernel)
#define FB_TH   8
#define HALO_R (FB_TH + 2)
#define HALO_C (W_ + 2)
#define XPLANE (HALO_R * HALO_C)

typedef __bf16 bf16x8 __attribute__((ext_vector_type(8)));
typedef __bf16 bf16x2 __attribute__((ext_vector_type(2)));
typedef float  f32x4  __attribute__((ext_vector_type(4)));
typedef unsigned int u32x4 __attribute__((ext_vector_type(4)));

__device__ __forceinline__ void gload16(const void* g, void* l) {
    __builtin_amdgcn_global_load_lds((const __attribute__((address_space(1))) void*)g,
                                     (__attribute__((address_space(3))) void*)l, 16, 0, 0);
}

__device__ __forceinline__ uint packbf2(float a, float b) {
    bf16x2 v; v[0] = (__bf16)a; v[1] = (__bf16)b;
    return __builtin_bit_cast(unsigned int, v);
}

// ---------- merged pre-kernel (champion R13): xpose (7424) + ctx (32) + wconv (36) ----------
// xt layout: [n][g][58 rows][58 pixels][4 slots][8 ic] bf16; octet o of pixel pix
// stored at slot o ^ ((pix>>1)&3)  (LDS bank swizzle; main's read applies same XOR).
// VECTORIZED: float4 global reads (448/row), dwordx4 global writes (232/row).
__global__ __launch_bounds__(256) void pre_kernel(
    const float* __restrict__ x, const float* __restrict__ c,
    const float* __restrict__ wgt, const float* __restrict__ bias,
    const float* __restrict__ cw,
    __bf16* __restrict__ xt, float* __restrict__ gctx, __bf16* __restrict__ wbf)
{
    const int bid = blockIdx.x;
    const int tid = threadIdx.x;

    if (bid < HP * GROUPS * N_) {                 // ---- xpose (one padded row) ----
        const int hh = bid % HP;
        const int g  = (bid / HP) & (GROUPS - 1);
        const int n  = bid / (HP * GROUPS);
        u32x4* drow4 = (u32x4*)(xt + ((size_t)(n * GROUPS + g) * HP + hh) * ROWB);  // 232 dwordx4
        const int h = hh - 1;
        if ((unsigned)h >= (unsigned)H_) {        // top/bottom halo row: zeros
            if (tid < ROW4) drow4[tid] = (u32x4){0u, 0u, 0u, 0u};
            return;
        }
        __shared__ float t[CPG][57];              // [ic][w]; pad 57 -> e-gather ~2-way
        const float* src = x + ((size_t)(n * CIN + g * CPG) * H_ + h) * W_;
        // load: 448 float4 jobs (ic 0..31, q 0..13), coalesced 224B runs per ic
        for (int j = tid; j < CPG * (W_ / 4); j += 256) {
            int ic = j / 14, q = j - ic * 14;
            f32x4 v = *(const f32x4*)&src[(size_t)ic * HW_ + q * 4];
            #pragma unroll
            for (int k = 0; k < 4; ++k) t[ic][q * 4 + k] = v[k];
        }
        __syncthreads();
        // store: 232 dwordx4 jobs; j -> pix=j>>2, slot=j&3, oct = slot ^ ((pix>>1)&3)
        if (tid < HP * 4) {
            int pix = tid >> 2;
            int oct = (tid & 3) ^ ((pix >> 1) & 3);
            int w = pix - 1;
            u32x4 o4 = {0u, 0u, 0u, 0u};
            if ((unsigned)w < (unsigned)W_) {
                #pragma unroll
                for (int dd = 0; dd < 4; ++dd)
                    o4[dd] = packbf2(t[oct * 8 + dd * 2][w], t[oct * 8 + dd * 2 + 1][w]);
            }
            drow4[tid] = o4;
        }
    } else if (bid < HP * GROUPS * N_ + N_) {     // ---- ctx ----
        const int n  = bid - HP * GROUPS * N_;
        const int oc = tid;
        const float* cn  = c  + n * CDIM;
        const float* cwo = cw + oc * CDIM;
        float s = bias[oc];
        #pragma unroll
        for (int d = 0; d < CDIM; ++d) s += cn[d] * cwo[d];
        gctx[n * COUT + oc] = s;
    } else {                                      // ---- wconv: bf16 [g][tap][oct][ocL][8] ----
        int j = (bid - (HP * GROUPS * N_ + N_)) * 256 + tid;
        int e   = j & 7;
        int r   = j >> 3;
        int ocL = r & 63;  r >>= 6;
        int o   = r & 3;   r >>= 2;               // ic octet
        int tap = r % 9;
        int g   = r / 9;
        int ic  = o * 8 + e;
        wbf[j] = (__bf16)wgt[((g * OPG + ocL) * CPG + ic) * 9 + tap];
    }
}

// ---------- main kernel: champion (R13 / 47.3us measured) ----------
__global__ __launch_bounds__(256, 4) void conv_main(
    const __bf16* __restrict__ xt, const __bf16* __restrict__ wbf,
    const float* __restrict__ gctx, float* __restrict__ out)
{
    __shared__ __align__(16) __bf16 x_lds[(STRIP_CHUNKS * 1024) / 2];   // 37888 B

    const int ht  = blockIdx.x;   // 0..6  (8-row strip)
    const int g   = blockIdx.y;   // 0..3
    const int n   = blockIdx.z;   // 0..31
    const int tid = threadIdx.x;  // 0..255 (4 waves)
    const int h0  = ht * TH;

    const int wv   = tid >> 6;       // 0..3
    const int lane = tid & 63;
    const int l15  = lane & 15;
    const int kh4  = lane >> 4;      // ic octet / D pixel-quad group
    const int p2   = (wv & 1) * 2;   // oc-tile pair base (0 or 2)
    const int ph   = wv >> 1;        // pixel half (14 tiles each)

    // ---- stage strip rows h0..h0+9 FIRST (latency overlaps loads below) ----
    {
        const char* sbase = (const char*)(xt + ((size_t)(n * GROUPS + g) * HP + h0) * ROWB);
        char* lbase = (char*)&x_lds[0];
        for (int ch = wv; ch < STRIP_CHUNKS; ch += 4)     // wave-uniform dest base
            gload16(sbase + ch * 1024 + lane * 16, lbase + ch * 1024);
        // (chunk 36 copies 768B of tail slack; stays inside d_ws, never read)
    }

    // ---- w-frags from pre-permuted global; PIN so compiler can't sink ----
    u32x4 a[2][9];
    {
        const __bf16* wgb = wbf + (size_t)g * (9 * 4 * OPG * 8);
        #pragma unroll
        for (int i = 0; i < 2; ++i)
            #pragma unroll
            for (int tap = 0; tap < 9; ++tap)
                a[i][tap] = *(const u32x4*)&wgb[(((tap * 4 + kh4) * OPG) + (p2 + i) * 16 + l15) * 8];
    }
    #pragma unroll
    for (int i = 0; i < 2; ++i)
        #pragma unroll
        for (int tap = 0; tap < 9; ++tap)
            asm volatile("" : "+v"(a[i][tap]));

    // ctx for this lane's oc (one per oc-tile) — coalesced 64B loads
    float ctxv[2];
    #pragma unroll
    for (int i = 0; i < 2; ++i)
        ctxv[i] = gctx[n * COUT + g * OPG + (p2 + i) * 16 + l15];

    __syncthreads();

    // lane's output rows: oc = g*OPG + (p2+i)*16 + l15
    float* outb0 = out + ((size_t)n * COUT + g * OPG + p2 * 16 + l15) * HW_ + h0 * W_;
    float* outb1 = outb0 + (size_t)16 * HW_;

    #pragma unroll 1
    for (int t = ph * 14; t < ph * 14 + 14; ++t) {
        int p  = t * 16 + l15;           // A-row pixel for LDS read
        int pr = p / W_;
        int pc = p - pr * W_;
        f32x4 acc0 = {ctxv[0], ctxv[0], ctxv[0], ctxv[0]};   // ctx as C-init
        f32x4 acc1 = {ctxv[1], ctxv[1], ctxv[1], ctxv[1]};
        #pragma unroll
        for (int kh = 0; kh < 3; ++kh) {
            #pragma unroll
            for (int kw = 0; kw < 3; ++kw) {
                int pix = pc + kw;
                int idx = (pr + kh) * ROWB + pix * CPG + ((kh4 ^ ((pix >> 1) & 3)) << 3);
                const bf16x8 b = *(const bf16x8*)&x_lds[idx];
                // swapped operands: D[m=pixel][n=oc]
                acc0 = __builtin_amdgcn_mfma_f32_16x16x32_bf16(
                           b, __builtin_bit_cast(bf16x8, a[0][kh * 3 + kw]), acc0, 0, 0, 0);
                acc1 = __builtin_amdgcn_mfma_f32_16x16x32_bf16(
                           b, __builtin_bit_cast(bf16x8, a[1][kh * 3 + kw]), acc1, 0, 0, 0);
            }
        }
        // lane writes 4 consecutive pixels for its oc in each oc-tile
        int p0 = t * 16 + kh4 * 4;
        *(f32x4*)&outb0[p0] = acc0;
        *(f32x4*)&outb1[p0] = acc1;
    }
}

// ---------- fallback (R2 structure) if workspace can't hold xt ----------
__global__ void ctx_kernel_fb(const float* __restrict__ c, const float* __restrict__ bias,
                              const float* __restrict__ cw, float* __restrict__ gctx) {
    const int n  = blockIdx.x;
    const int oc = threadIdx.x;
    const float* cn  = c  + n * CDIM;
    const float* cwo = cw + oc * CDIM;
    float s = bias[oc];
    #pragma unroll
    for (int d = 0; d < CDIM; ++d) s += cn[d] * cwo[d];
    gctx[n * COUT + oc] = s;
}
__global__ void wconv_kernel_fb(const float* __restrict__ wgt, __bf16* __restrict__ wbf) {
    int j = blockIdx.x * 256 + threadIdx.x;
    int e   = j & 7;
    int r   = j >> 3;
    int ocL = r & 63;  r >>= 6;
    int o   = r & 3;   r >>= 2;
    int tap = r % 9;
    int g   = r / 9;
    int ic  = o * 8 + e;
    wbf[j] = (__bf16)wgt[((g * OPG + ocL) * CPG + ic) * 9 + tap];
}
__global__ __launch_bounds__(512, 4) void ctx_conv_fb(
    const float* __restrict__ x, const __bf16* __restrict__ wbf,
    const float* __restrict__ gctx, float* __restrict__ out)
{
    __shared__ __align__(16) __bf16 x_lds[XPLANE][CPG];
    const int ht  = blockIdx.x;
    const int g   = blockIdx.y;
    const int n   = blockIdx.z;
    const int tid = threadIdx.x;
    const int h0  = ht * FB_TH;
    const int wv   = tid >> 6;
    const int lane = tid & 63;
    const int l15  = lane & 15;
    const int kh4  = lane >> 4;
    const int p2   = (wv & 1) * 2;
    const int pq   = wv >> 1;

    bf16x8 a[2][9];
    {
        const __bf16* wgb = wbf + (size_t)g * (9 * 4 * OPG * 8);
        #pragma unroll
        for (int i = 0; i < 2; ++i)
            #pragma unroll
            for (int tap = 0; tap < 9; ++tap)
                a[i][tap] = *(const bf16x8*)&wgb[(((tap * 4 + kh4) * OPG) + (p2 + i) * 16 + l15) * 8];
    }
    float ctxv[2][4];
    #pragma unroll
    for (int i = 0; i < 2; ++i)
        #pragma unroll
        for (int r = 0; r < 4; ++r)
            ctxv[i][r] = gctx[n * COUT + g * OPG + (p2 + i) * 16 + kh4 * 4 + r];
    {
        const float* xg = x + ((size_t)n * CIN + g * CPG) * HW_;
        for (int j = tid; j < 4 * XPLANE; j += 512) {
            int pix = j >> 2;
            int oct = j & 3;
            int hr = pix / HALO_C;
            int wc = pix - hr * HALO_C;
            int hg  = h0 - 1 + hr;
            int wg2 = wc - 1;
            bool valid = ((unsigned)hg < (unsigned)H_) && ((unsigned)wg2 < (unsigned)W_);
            const float* src = xg + (size_t)(oct * 8) * HW_ + hg * W_ + wg2;
            bf16x8 v;
            #pragma unroll
            for (int e = 0; e < 8; ++e)
                v[e] = (__bf16)(valid ? src[(size_t)e * HW_] : 0.f);
            *(bf16x8*)&x_lds[pix][oct * 8] = v;
        }
    }
    __syncthreads();
    float* outb = out + ((size_t)n * COUT + g * OPG + p2 * 16 + kh4 * 4) * HW_ + h0 * W_;
    #pragma unroll 1
    for (int t = pq * 7; t < pq * 7 + 7; ++t) {
        int p  = t * 16 + l15;
        int pr = p / W_;
        int pc = p - pr * W_;
        f32x4 acc0 = {0.f, 0.f, 0.f, 0.f};
        f32x4 acc1 = {0.f, 0.f, 0.f, 0.f};
        #pragma unroll
        for (int kh = 0; kh < 3; ++kh) {
            #pragma unroll
            for (int kw = 0; kw < 3; ++kw) {
                const bf16x8 b = *(const bf16x8*)&x_lds[(pr + kh) * HALO_C + (pc + kw)][kh4 * 8];
                acc0 = __builtin_amdgcn_mfma_f32_16x16x32_bf16(a[0][kh * 3 + kw], b, acc0, 0, 0, 0);
                acc1 = __builtin_amdgcn_mfma_f32_16x16x32_bf16(a[1][kh * 3 + kw], b, acc1, 0, 0, 0);
            }
        }
        #pragma unroll
        for (int r = 0; r < 4; ++r)
            outb[(size_t)r * HW_ + p] = acc0[r] + ctxv[0][r];
        #pragma unroll
        for (int r = 0; r < 4; ++r)
            outb[(size_t)(16 + r) * HW_ + p] = acc1[r] + ctxv[1][r];
    }
}

extern "C" void kernel_launch(void* const* d_in, const int* in_sizes, int n_in,
                              void* d_out, int out_size, void* d_ws, size_t ws_size,
                              hipStream_t stream) {
    const float* x    = (const float*)d_in[0];
    const float* c    = (const float*)d_in[1];
    const float* wgt  = (const float*)d_in[2];
    const float* bias = (const float*)d_in[3];
    const float* cw   = (const float*)d_in[4];
    float* out = (float*)d_out;

    const size_t XT_BYTES   = (size_t)N_ * GROUPS * HP * HP * CPG * 2;   // 27,557,888
    const size_t GCTX_BYTES = (size_t)N_ * COUT * 4;                     // 32,768
    const size_t WBF_BYTES  = (size_t)COUT * CPG * 9 * 2;                // 147,456
    const size_t NEEDED     = XT_BYTES + GCTX_BYTES + WBF_BYTES;

    if (ws_size >= NEEDED) {
        __bf16* xt   = (__bf16*)d_ws;
        float*  gctx = (float*)((char*)d_ws + XT_BYTES);
        __bf16* wbf  = (__bf16*)((char*)d_ws + XT_BYTES + GCTX_BYTES);

        const int nxpose = HP * GROUPS * N_;                       // 7424
        const int npre   = nxpose + N_ + (COUT * CPG * 9) / 256;   // +32 +36
        pre_kernel<<<dim3(npre), 256, 0, stream>>>(x, c, wgt, bias, cw, xt, gctx, wbf);

        dim3 grid(H_ / TH, GROUPS, N_);   // (7, 4, 32) = 896 blocks x 256 thr
        conv_main<<<grid, 256, 0, stream>>>(xt, wbf, gctx, out);
    } else {
        float*  gctx = (float*)d_ws;
        __bf16* wbf  = (__bf16*)((char*)d_ws + 32768);
        ctx_kernel_fb<<<dim3(N_), 256, 0, stream>>>(c, bias, cw, gctx);
        wconv_kernel_fb<<<dim3((COUT * CPG * 9) / 256), 256, 0, stream>>>(wgt, wbf);
        dim3 grid(H_ / FB_TH, GROUPS, N_);
        ctx_conv_fb<<<grid, 512, 0, stream>>>(x, wbf, gctx, out);
    }
}